// Round 1
// baseline (660.497 us; speedup 1.0000x reference)
//
#include <hip/hip_runtime.h>

typedef unsigned short u16;
typedef unsigned int   u32;
typedef __attribute__((ext_vector_type(8))) __bf16 bf16x8;
typedef __attribute__((ext_vector_type(4))) float   f32x4;

#define MROWS 16400     // 16 * 1025
#define NPADROWS 16512  // 129 * 128
#define KD 1024

__device__ __forceinline__ u16 f2b(float f) {
  union { float f; u32 u; } x; x.f = f;
  return (u16)((x.u + 0x7FFFu + ((x.u >> 16) & 1u)) >> 16);
}
__device__ __forceinline__ float b2f(u16 h) {
  union { u32 u; float f; } x; x.u = ((u32)h) << 16;
  return x.f;
}

// ---------------------------------------------------------------------------
// Transpose + convert weights: W[k][n] f32 -> T[n][k] bf16  (z selects matrix)
// ---------------------------------------------------------------------------
__global__ __launch_bounds__(256) void k_wtrans(
    const float* __restrict__ W0, const float* __restrict__ W1,
    const float* __restrict__ W2, const float* __restrict__ W3,
    u16* __restrict__ T)
{
  __shared__ float tile[32][33];
  int z = blockIdx.z;
  const float* W = (z == 0) ? W0 : (z == 1) ? W1 : (z == 2) ? W2 : W3;
  u16* Tz = T + (size_t)z * KD * KD;
  int tx = threadIdx.x, ty = threadIdx.y;
  int k0 = blockIdx.x * 32, n0 = blockIdx.y * 32;
#pragma unroll
  for (int r = ty; r < 32; r += 8)
    tile[r][tx] = W[(size_t)(k0 + r) * KD + n0 + tx];
  __syncthreads();
#pragma unroll
  for (int r = ty; r < 32; r += 8)
    Tz[(size_t)(n0 + r) * KD + k0 + tx] = f2b(tile[tx][r]);
}

// ---------------------------------------------------------------------------
// bf16 MFMA GEMM: C[M,1024] = A[M,1024] @ B[1024,1024]
// A: fp32 (converted in staging) or bf16; B: pre-transposed bf16 Bt[n][k].
// 128x128 tile, BK=32, 4 waves (2x2), 4x4 fragments of 16x16x32 per wave.
// ---------------------------------------------------------------------------
template<bool A_BF16, bool OUT_FP32>
__global__ __launch_bounds__(256) void k_gemm(
    const void* __restrict__ A0v, const void* __restrict__ A1v, const void* __restrict__ A2v,
    const u16* __restrict__ Bt, long long b_zstride,
    u16* __restrict__ Cb0, u16* __restrict__ Cb1, u16* __restrict__ Cb2,
    float* __restrict__ Cf, const float* __restrict__ bias)
{
  __shared__ u16 sa[128 * 32];
  __shared__ u16 sb[128 * 32];

  int z = blockIdx.z;
  const void* Av = (z == 0) ? A0v : (z == 1) ? A1v : A2v;
  const u16* B = Bt + (size_t)(z * b_zstride);
  u16* Cb = (z == 0) ? Cb0 : (z == 1) ? Cb1 : Cb2;

  int t = threadIdx.x;
  int w = t >> 6, l = t & 63;
  int lrow = l & 15, kgrp = l >> 4;
  int wm = (w >> 1) * 64, wn = (w & 1) * 64;
  int bm = blockIdx.x, bn = blockIdx.y;

  f32x4 acc[4][4] = {};

  // A staging: thread covers row=t>>1, k-half=(t&1)*16 (16 elems)
  int arow = t >> 1;
  int ak0 = (t & 1) * 16;
  int crow = bm * 128 + arow;
  if (crow > MROWS - 1) crow = MROWS - 1;   // clamp tail-tile rows
  const float* agf = (const float*)Av + (size_t)crow * KD + ak0;
  const u16*  agb = (const u16*) Av + (size_t)crow * KD + ak0;
  u16* adst = &sa[arow * 32 + ak0];

  // B staging: 2 chunks of 8 bf16 per thread, LDS-linear in chunk index
  int c0 = (w * 2 + 0) * 64 + l, c1 = (w * 2 + 1) * 64 + l;
  const u16* bg0 = B + (size_t)(bn * 128 + (c0 >> 2)) * KD + (c0 & 3) * 8;
  const u16* bg1 = B + (size_t)(bn * 128 + (c1 >> 2)) * KD + (c1 & 3) * 8;

  for (int kt = 0; kt < KD / 32; ++kt) {
    uint4 bv0 = *(const uint4*)bg0;
    uint4 bv1 = *(const uint4*)bg1;
    uint4 pa0, pa1;
    if constexpr (A_BF16) {
      pa0 = *(const uint4*)agb;
      pa1 = *(const uint4*)(agb + 8);
    } else {
      const float4 f0 = *(const float4*)(agf + 0);
      const float4 f1 = *(const float4*)(agf + 4);
      const float4 f2 = *(const float4*)(agf + 8);
      const float4 f3 = *(const float4*)(agf + 12);
      pa0.x = (u32)f2b(f0.x) | ((u32)f2b(f0.y) << 16);
      pa0.y = (u32)f2b(f0.z) | ((u32)f2b(f0.w) << 16);
      pa0.z = (u32)f2b(f1.x) | ((u32)f2b(f1.y) << 16);
      pa0.w = (u32)f2b(f1.z) | ((u32)f2b(f1.w) << 16);
      pa1.x = (u32)f2b(f2.x) | ((u32)f2b(f2.y) << 16);
      pa1.y = (u32)f2b(f2.z) | ((u32)f2b(f2.w) << 16);
      pa1.z = (u32)f2b(f3.x) | ((u32)f2b(f3.y) << 16);
      pa1.w = (u32)f2b(f3.z) | ((u32)f2b(f3.w) << 16);
    }
    *(uint4*)adst       = pa0;
    *(uint4*)(adst + 8) = pa1;
    *(uint4*)&sb[c0 * 8] = bv0;
    *(uint4*)&sb[c1 * 8] = bv1;
    __syncthreads();

    bf16x8 af[4], bfr[4];
#pragma unroll
    for (int fm = 0; fm < 4; ++fm)
      af[fm] = *(const bf16x8*)&sa[(wm + fm * 16 + lrow) * 32 + kgrp * 8];
#pragma unroll
    for (int fn = 0; fn < 4; ++fn)
      bfr[fn] = *(const bf16x8*)&sb[(wn + fn * 16 + lrow) * 32 + kgrp * 8];
#pragma unroll
    for (int fm = 0; fm < 4; ++fm)
#pragma unroll
      for (int fn = 0; fn < 4; ++fn)
        acc[fm][fn] = __builtin_amdgcn_mfma_f32_16x16x32_bf16(af[fm], bfr[fn], acc[fm][fn], 0, 0, 0);

    __syncthreads();
    agf += 32; agb += 32; bg0 += 32; bg1 += 32;
  }

  // epilogue: C/D layout col=l&15, row=(l>>4)*4+reg  [m89-verified]
#pragma unroll
  for (int fm = 0; fm < 4; ++fm) {
#pragma unroll
    for (int fn = 0; fn < 4; ++fn) {
      int gcol = bn * 128 + wn + fn * 16 + lrow;
#pragma unroll
      for (int r = 0; r < 4; ++r) {
        int grow = bm * 128 + wm + fm * 16 + kgrp * 4 + r;
        if constexpr (OUT_FP32) {
          if (grow < MROWS)
            Cf[(size_t)grow * KD + gcol] = acc[fm][fn][r] + bias[gcol];
        } else {
          Cb[(size_t)grow * KD + gcol] = f2b(acc[fm][fn][r]);  // padded buffer
        }
      }
    }
  }
}

// ---------------------------------------------------------------------------
// Sparse nearby attention for queries i>=1: <=25 window keys + BOS key 0.
// One 256-thread block per (b, i). fp32 softmax, bf16 gathers.
// ---------------------------------------------------------------------------
__global__ __launch_bounds__(256) void k_attn_nb(
    const u16* __restrict__ Qp, const u16* __restrict__ Kp,
    const u16* __restrict__ Vp, u16* __restrict__ AO)
{
  __shared__ float qrow[1024];
  __shared__ int   keys[26];
  __shared__ float dots[416];
  __shared__ float probs[416];

  int t = threadIdx.x;
  int b = blockIdx.x >> 10;
  int pm = blockIdx.x & 1023;
  int i = 1 + pm;
  int pi = pm >> 5, pj = pm & 31;
  size_t rowbase = (size_t)b * 1025;

  { // stage q row as fp32 (4 elems/thread)
    const u16* qp = Qp + (rowbase + i) * 1024 + t * 4;
    ushort4 qv = *(const ushort4*)qp;
    qrow[t * 4 + 0] = b2f(qv.x); qrow[t * 4 + 1] = b2f(qv.y);
    qrow[t * 4 + 2] = b2f(qv.z); qrow[t * 4 + 3] = b2f(qv.w);
  }
  if (t < 25) {
    int r = pi + t / 5 - 2, c = pj + (t % 5) - 2;
    keys[t] = (r >= 0 && r < 32 && c >= 0 && c < 32) ? (1 + r * 32 + c) : -1;
  } else if (t == 25) {
    keys[25] = 0;  // BOS column always unmasked
  }
  __syncthreads();

  // dots: 16 heads x 26 slots = 416 work items
  for (int s = t; s < 416; s += 256) {
    int h = s / 26, j = s - h * 26;
    int key = keys[j];
    float d = -3.0e38f;
    if (key >= 0) {
      const u16* kp = Kp + (rowbase + key) * 1024 + h * 64;
      const float* qh = &qrow[h * 64];
      float sum = 0.f;
#pragma unroll
      for (int e = 0; e < 64; e += 4) {
        ushort4 kv = *(const ushort4*)(kp + e);
        sum += qh[e + 0] * b2f(kv.x) + qh[e + 1] * b2f(kv.y)
             + qh[e + 2] * b2f(kv.z) + qh[e + 3] * b2f(kv.w);
      }
      d = sum * 0.125f;   // DIM_HEAD^-0.5
    }
    dots[s] = d;
  }
  __syncthreads();

  if (t < 16) {  // per-head softmax over 26 slots
    float m = -3.0e38f;
    for (int j = 0; j < 26; ++j) m = fmaxf(m, dots[t * 26 + j]);
    float sum = 0.f;
    for (int j = 0; j < 26; ++j) {
      float p = __expf(dots[t * 26 + j] - m);
      probs[t * 26 + j] = p; sum += p;
    }
    float inv = 1.f / sum;
    for (int j = 0; j < 26; ++j) probs[t * 26 + j] *= inv;
  }
  __syncthreads();

  // PV: thread t owns 4 consecutive output dims c0 = t*4 (head h = t>>4)
  int h = t >> 4;
  int c0 = t * 4;
  float a0 = 0, a1 = 0, a2 = 0, a3 = 0;
  const float* ph = &probs[h * 26];
#pragma unroll
  for (int j = 0; j < 26; ++j) {
    int key = keys[j];
    if (key < 0) continue;
    float p = ph[j];
    const u16* vp = Vp + (rowbase + key) * 1024 + c0;
    ushort4 vv = *(const ushort4*)vp;
    a0 += p * b2f(vv.x); a1 += p * b2f(vv.y);
    a2 += p * b2f(vv.z); a3 += p * b2f(vv.w);
  }
  ushort4 o;
  o.x = f2b(a0); o.y = f2b(a1); o.z = f2b(a2); o.w = f2b(a3);
  *(ushort4*)&AO[(rowbase + i) * 1024 + c0] = o;
}

// ---------------------------------------------------------------------------
// Dense attention for BOS query (i=0): attends to all 1025 keys.
// One block per (b, h); 256 blocks total.
// ---------------------------------------------------------------------------
__global__ __launch_bounds__(256) void k_attn_row0(
    const u16* __restrict__ Qp, const u16* __restrict__ Kp,
    const u16* __restrict__ Vp, u16* __restrict__ AO)
{
  __shared__ float q0[64];
  __shared__ float pr[1025];
  __shared__ float red[256];
  int t = threadIdx.x;
  int b = blockIdx.x >> 4, h = blockIdx.x & 15;
  size_t rowbase = (size_t)b * 1025;

  if (t < 64) q0[t] = b2f(Qp[rowbase * 1024 + h * 64 + t]);
  __syncthreads();

  float lmax = -3.0e38f;
  for (int j = t; j < 1025; j += 256) {
    const u16* kp = Kp + (rowbase + j) * 1024 + h * 64;
    float s = 0.f;
#pragma unroll
    for (int e = 0; e < 64; e += 4) {
      ushort4 kv = *(const ushort4*)(kp + e);
      s += q0[e + 0] * b2f(kv.x) + q0[e + 1] * b2f(kv.y)
         + q0[e + 2] * b2f(kv.z) + q0[e + 3] * b2f(kv.w);
    }
    s *= 0.125f;
    pr[j] = s;
    lmax = fmaxf(lmax, s);
  }
  red[t] = lmax; __syncthreads();
  for (int s = 128; s > 0; s >>= 1) {
    if (t < s) red[t] = fmaxf(red[t], red[t + s]);
    __syncthreads();
  }
  float m = red[0]; __syncthreads();

  float lsum = 0.f;
  for (int j = t; j < 1025; j += 256) {
    float p = __expf(pr[j] - m);
    pr[j] = p; lsum += p;
  }
  red[t] = lsum; __syncthreads();
  for (int s = 128; s > 0; s >>= 1) {
    if (t < s) red[t] += red[t + s];
    __syncthreads();
  }
  float inv = 1.f / red[0]; __syncthreads();

  // PV: d = t&63, 4 j-strided groups, then cross-group reduce
  int d = t & 63, grp = t >> 6;
  float a = 0.f;
  for (int j = grp; j < 1025; j += 4)
    a += pr[j] * b2f(Vp[(rowbase + j) * 1024 + h * 64 + d]);
  red[t] = a; __syncthreads();
  if (t < 64) {
    float tot = (red[t] + red[t + 64]) + (red[t + 128] + red[t + 192]);
    AO[rowbase * 1024 + h * 64 + t] = f2b(tot * inv);
  }
}

// ---------------------------------------------------------------------------
extern "C" void kernel_launch(void* const* d_in, const int* in_sizes, int n_in,
                              void* d_out, int out_size, void* d_ws, size_t ws_size,
                              hipStream_t stream) {
  const float* q  = (const float*)d_in[0];
  const float* k  = (const float*)d_in[1];
  const float* v  = (const float*)d_in[2];
  const float* Wq = (const float*)d_in[3];
  const float* Wk = (const float*)d_in[4];
  const float* Wv = (const float*)d_in[5];
  const float* Wo = (const float*)d_in[6];
  const float* bo = (const float*)d_in[7];
  float* out = (float*)d_out;

  // workspace carve (u16 units):
  //   wt:  4 * 1M          (Wq^T, Wk^T, Wv^T, Wo^T bf16)
  //   Qp, Kp, Vp, AO: 16512*1024 each (bf16, padded to 129*128 rows)
  // total = 143.7 MB
  u16* wt = (u16*)d_ws;
  u16* Qp = wt + (size_t)4 * 1024 * 1024;
  u16* Kp = Qp + (size_t)NPADROWS * 1024;
  u16* Vp = Kp + (size_t)NPADROWS * 1024;
  u16* AO = Vp + (size_t)NPADROWS * 1024;

  k_wtrans<<<dim3(32, 32, 4), dim3(32, 8), 0, stream>>>(Wq, Wk, Wv, Wo, wt);

  // Q/K/V projections: A fp32 (d_in), C bf16 (padded)
  k_gemm<false, false><<<dim3(129, 8, 3), 256, 0, stream>>>(
      q, k, v, wt, (long long)1024 * 1024, Qp, Kp, Vp, nullptr, nullptr);

  k_attn_nb<<<16 * 1024, 256, 0, stream>>>(Qp, Kp, Vp, AO);
  k_attn_row0<<<256, 256, 0, stream>>>(Qp, Kp, Vp, AO);

  // output projection: A bf16 (AO), C fp32 (+bias), row-masked store
  k_gemm<true, true><<<dim3(129, 8, 1), 256, 0, stream>>>(
      AO, nullptr, nullptr, wt + (size_t)3 * 1024 * 1024, 0,
      nullptr, nullptr, nullptr, out, bo);
}

// Round 2
// 452.050 us; speedup vs baseline: 1.4611x; 1.4611x over previous
//
#include <hip/hip_runtime.h>

typedef unsigned short u16;
typedef unsigned int   u32;
typedef __attribute__((ext_vector_type(8))) __bf16 bf16x8;
typedef __attribute__((ext_vector_type(4))) float   f32x4;

#define MROWS 16400     // 16 * 1025
#define NPADROWS 16512  // 129 * 128
#define KD 1024
#define MATEL ((size_t)NPADROWS * KD)   // elems per padded matrix

__device__ __forceinline__ u16 f2b(float f) {
  union { float f; u32 u; } x; x.f = f;
  return (u16)((x.u + 0x7FFFu + ((x.u >> 16) & 1u)) >> 16);
}
__device__ __forceinline__ float b2f(u16 h) {
  union { u32 u; float f; } x; x.u = ((u32)h) << 16;
  return x.f;
}

__device__ __forceinline__ void gll16(const u16* g, u16* l) {
  __builtin_amdgcn_global_load_lds(
      (const __attribute__((address_space(1))) void*)g,
      (__attribute__((address_space(3))) void*)l, 16, 0, 0);
}

// ---------------------------------------------------------------------------
// Transpose + convert weights: W[k][n] f32 -> T[n][k] bf16  (z selects matrix)
// ---------------------------------------------------------------------------
__global__ __launch_bounds__(256) void k_wtrans(
    const float* __restrict__ W0, const float* __restrict__ W1,
    const float* __restrict__ W2, const float* __restrict__ W3,
    u16* __restrict__ T)
{
  __shared__ float tile[32][33];
  int z = blockIdx.z;
  const float* W = (z == 0) ? W0 : (z == 1) ? W1 : (z == 2) ? W2 : W3;
  u16* Tz = T + (size_t)z * KD * KD;
  int tx = threadIdx.x, ty = threadIdx.y;
  int k0 = blockIdx.x * 32, n0 = blockIdx.y * 32;
#pragma unroll
  for (int r = ty; r < 32; r += 8)
    tile[r][tx] = W[(size_t)(k0 + r) * KD + n0 + tx];
  __syncthreads();
#pragma unroll
  for (int r = ty; r < 32; r += 8)
    Tz[(size_t)(n0 + r) * KD + k0 + tx] = f2b(tile[tx][r]);
}

// ---------------------------------------------------------------------------
// Convert q,k,v fp32 -> padded bf16 (zero tail rows). 8 elems/thread.
// ---------------------------------------------------------------------------
__global__ __launch_bounds__(256) void k_convert(
    const float* __restrict__ q, const float* __restrict__ k,
    const float* __restrict__ v, u16* __restrict__ dst)
{
  const size_t CH_PER_MAT = MATEL / 8;
  const size_t total = 3 * CH_PER_MAT;
  for (size_t c = (size_t)blockIdx.x * 256 + threadIdx.x; c < total;
       c += (size_t)gridDim.x * 256) {
    size_t z = c / CH_PER_MAT;
    size_t r = c - z * CH_PER_MAT;
    size_t row = r >> 7;
    int col8 = (int)(r & 127) * 8;
    u16* o = dst + z * MATEL + row * KD + col8;
    if (row < MROWS) {
      const float* s = ((z == 0) ? q : (z == 1) ? k : v) + row * KD + col8;
      float4 f0 = *(const float4*)s;
      float4 f1 = *(const float4*)(s + 4);
      ushort4 o0; o0.x = f2b(f0.x); o0.y = f2b(f0.y); o0.z = f2b(f0.z); o0.w = f2b(f0.w);
      ushort4 o1; o1.x = f2b(f1.x); o1.y = f2b(f1.y); o1.z = f2b(f1.z); o1.w = f2b(f1.w);
      *(ushort4*)o = o0; *(ushort4*)(o + 4) = o1;
    } else {
      ushort4 zz; zz.x = zz.y = zz.z = zz.w = 0;
      *(ushort4*)o = zz; *(ushort4*)(o + 4) = zz;
    }
  }
}

// ---------------------------------------------------------------------------
// bf16 MFMA GEMM (m97 structure): C[16512,1024] = A @ B^T-stored.
// 128x128 tile, BK=32, 4 waves 2x2, global_load_lds 16B staging.
// 1-D grid with bijective XCD swizzle, bn-fastest for A-panel L2 reuse.
// ---------------------------------------------------------------------------
template<bool OUT_FP32>
__global__ __launch_bounds__(256) void k_gemm(
    const u16* __restrict__ Ab, const u16* __restrict__ Bt,
    u16* __restrict__ Cb, float* __restrict__ Cf,
    const float* __restrict__ bias, int nwg)
{
  __shared__ u16 sa[128 * 32];
  __shared__ u16 sb[128 * 32];

  int lin = blockIdx.x;
  int cpx = nwg >> 3;                       // nwg % 8 == 0 guaranteed
  int swz = (lin & 7) * cpx + (lin >> 3);   // bijective XCD swizzle
  int bn = swz & 7;
  int rest = swz >> 3;
  int bm = rest % 129;
  int z  = rest / 129;

  int t = threadIdx.x;
  int w = t >> 6, l = t & 63;
  int lrow = l & 15, kgrp = l >> 4;
  int wm = (w >> 1) * 64, wn = (w & 1) * 64;

  // staging geometry: wave w, issue q covers LDS rows q*64 + w*16 .. +15
  int srow = w * 16 + (l >> 2);
  int scol = (l & 3) * 8;
  const u16* gA  = Ab + (size_t)z * MATEL + (size_t)(bm * 128 + srow) * KD + scol;
  const u16* gA2 = gA + (size_t)64 * KD;
  const u16* gB  = Bt + (size_t)z * (1024 * 1024) + (size_t)(bn * 128 + srow) * KD + scol;
  const u16* gB2 = gB + (size_t)64 * KD;
  u16* lA0 = &sa[w * 512];
  u16* lA1 = &sa[2048 + w * 512];
  u16* lB0 = &sb[w * 512];
  u16* lB1 = &sb[2048 + w * 512];

  f32x4 acc[4][4] = {};

  for (int kt = 0; kt < KD / 32; ++kt) {
    gll16(gA,  lA0);
    gll16(gA2, lA1);
    gll16(gB,  lB0);
    gll16(gB2, lB1);
    __syncthreads();   // compiler drains vmcnt before barrier

    bf16x8 af[4], bfr[4];
#pragma unroll
    for (int fm = 0; fm < 4; ++fm)
      af[fm] = *(const bf16x8*)&sa[(wm + fm * 16 + lrow) * 32 + kgrp * 8];
#pragma unroll
    for (int fn = 0; fn < 4; ++fn)
      bfr[fn] = *(const bf16x8*)&sb[(wn + fn * 16 + lrow) * 32 + kgrp * 8];
#pragma unroll
    for (int fm = 0; fm < 4; ++fm)
#pragma unroll
      for (int fn = 0; fn < 4; ++fn)
        acc[fm][fn] = __builtin_amdgcn_mfma_f32_16x16x32_bf16(af[fm], bfr[fn], acc[fm][fn], 0, 0, 0);

    __syncthreads();
    gA += 32; gA2 += 32; gB += 32; gB2 += 32;
  }

  // epilogue: C/D layout col=l&15, row=(l>>4)*4+reg  [m89-verified]
#pragma unroll
  for (int fm = 0; fm < 4; ++fm) {
#pragma unroll
    for (int fn = 0; fn < 4; ++fn) {
      int gcol = bn * 128 + wn + fn * 16 + lrow;
#pragma unroll
      for (int r = 0; r < 4; ++r) {
        int grow = bm * 128 + wm + fm * 16 + kgrp * 4 + r;
        if constexpr (OUT_FP32) {
          if (grow < MROWS)
            Cf[(size_t)grow * KD + gcol] = acc[fm][fn][r] + bias[gcol];
        } else {
          Cb[(size_t)z * MATEL + (size_t)grow * KD + gcol] = f2b(acc[fm][fn][r]);
        }
      }
    }
  }
}

// ---------------------------------------------------------------------------
// Sparse nearby attention, queries i>=1: <=25 window keys + BOS key 0.
// One 256-thread block per (b, i). Wave-parallel dots + softmax.
// ---------------------------------------------------------------------------
__global__ __launch_bounds__(256) void k_attn_nb(
    const u16* __restrict__ Qp, const u16* __restrict__ Kp,
    const u16* __restrict__ Vp, u16* __restrict__ AO)
{
  __shared__ float qrow[1024];
  __shared__ int   keys[26];
  __shared__ float dots[416];
  __shared__ float probs[416];

  int t = threadIdx.x;
  int b = blockIdx.x >> 10;
  int pm = blockIdx.x & 1023;
  int i = 1 + pm;
  int pi = pm >> 5, pj = pm & 31;
  size_t rowbase = (size_t)b * 1025;

  { // stage q row as fp32 (4 elems/thread)
    ushort4 qv = *(const ushort4*)(Qp + (rowbase + i) * 1024 + t * 4);
    qrow[t * 4 + 0] = b2f(qv.x); qrow[t * 4 + 1] = b2f(qv.y);
    qrow[t * 4 + 2] = b2f(qv.z); qrow[t * 4 + 3] = b2f(qv.w);
  }
  if (t < 25) {
    int r = pi + t / 5 - 2, c = pj + (t % 5) - 2;
    keys[t] = (r >= 0 && r < 32 && c >= 0 && c < 32) ? (1 + r * 32 + c) : -1;
  } else if (t == 25) {
    keys[25] = 0;  // BOS column always unmasked
  }
  __syncthreads();

  // dots: 416 items (16 heads x 26 slots), 4 lanes cooperate per item
  int g = t >> 2, e = t & 3;
#pragma unroll
  for (int p = 0; p < 7; ++p) {
    int s = p * 64 + g;
    float sum = 0.f;
    int key = -1;
    if (s < 416) {
      int h = s / 26, j = s - h * 26;
      key = keys[j];
      if (key >= 0) {
        const u16* kp = Kp + (rowbase + key) * 1024 + h * 64 + e * 16;
        const float* qh = &qrow[h * 64 + e * 16];
        uint4 kv0 = *(const uint4*)kp;
        uint4 kv1 = *(const uint4*)(kp + 8);
        u32 uu[8] = {kv0.x, kv0.y, kv0.z, kv0.w, kv1.x, kv1.y, kv1.z, kv1.w};
#pragma unroll
        for (int u = 0; u < 8; ++u) {
          float lo = __uint_as_float(uu[u] << 16);
          float hi = __uint_as_float(uu[u] & 0xffff0000u);
          sum += qh[u * 2] * lo + qh[u * 2 + 1] * hi;
        }
      }
    }
    sum += __shfl_xor(sum, 1);
    sum += __shfl_xor(sum, 2);
    if (s < 416 && e == 0)
      dots[s] = (key >= 0) ? sum * 0.125f : -3.0e38f;
  }
  __syncthreads();

  { // softmax: 16 lanes per head, butterfly reduce
    int hh = t >> 4, sl = t & 15;
    float d0 = dots[hh * 26 + sl];
    float d1 = (sl < 10) ? dots[hh * 26 + 16 + sl] : -3.0e38f;
    float m = fmaxf(d0, d1);
#pragma unroll
    for (int o = 8; o; o >>= 1) m = fmaxf(m, __shfl_xor(m, o));
    float p0 = __expf(d0 - m);
    float p1 = (sl < 10) ? __expf(d1 - m) : 0.f;
    float sum = p0 + p1;
#pragma unroll
    for (int o = 8; o; o >>= 1) sum += __shfl_xor(sum, o);
    float inv = 1.f / sum;
    probs[hh * 26 + sl] = p0 * inv;
    if (sl < 10) probs[hh * 26 + 16 + sl] = p1 * inv;
  }
  __syncthreads();

  // PV: thread t owns 4 consecutive output dims c0 = t*4 (head h = t>>4)
  int h = t >> 4;
  int c0 = t * 4;
  float a0 = 0, a1 = 0, a2 = 0, a3 = 0;
  const float* ph = &probs[h * 26];
#pragma unroll
  for (int j = 0; j < 26; ++j) {
    int key = keys[j];
    if (key < 0) continue;
    float p = ph[j];
    ushort4 vv = *(const ushort4*)(Vp + (rowbase + key) * 1024 + c0);
    a0 += p * b2f(vv.x); a1 += p * b2f(vv.y);
    a2 += p * b2f(vv.z); a3 += p * b2f(vv.w);
  }
  ushort4 o;
  o.x = f2b(a0); o.y = f2b(a1); o.z = f2b(a2); o.w = f2b(a3);
  *(ushort4*)&AO[(rowbase + i) * 1024 + c0] = o;
}

// ---------------------------------------------------------------------------
// Dense attention for BOS query (i=0): attends to all 1025 keys.
// ---------------------------------------------------------------------------
__global__ __launch_bounds__(256) void k_attn_row0(
    const u16* __restrict__ Qp, const u16* __restrict__ Kp,
    const u16* __restrict__ Vp, u16* __restrict__ AO)
{
  __shared__ float q0[64];
  __shared__ float pr[1025];
  __shared__ float red[256];
  int t = threadIdx.x;
  int b = blockIdx.x >> 4, h = blockIdx.x & 15;
  size_t rowbase = (size_t)b * 1025;

  if (t < 64) q0[t] = b2f(Qp[rowbase * 1024 + h * 64 + t]);
  __syncthreads();

  float lmax = -3.0e38f;
  for (int j = t; j < 1025; j += 256) {
    const u16* kp = Kp + (rowbase + j) * 1024 + h * 64;
    float s = 0.f;
#pragma unroll
    for (int e = 0; e < 64; e += 4) {
      ushort4 kv = *(const ushort4*)(kp + e);
      s += q0[e + 0] * b2f(kv.x) + q0[e + 1] * b2f(kv.y)
         + q0[e + 2] * b2f(kv.z) + q0[e + 3] * b2f(kv.w);
    }
    s *= 0.125f;
    pr[j] = s;
    lmax = fmaxf(lmax, s);
  }
  red[t] = lmax; __syncthreads();
  for (int s = 128; s > 0; s >>= 1) {
    if (t < s) red[t] = fmaxf(red[t], red[t + s]);
    __syncthreads();
  }
  float m = red[0]; __syncthreads();

  float lsum = 0.f;
  for (int j = t; j < 1025; j += 256) {
    float p = __expf(pr[j] - m);
    pr[j] = p; lsum += p;
  }
  red[t] = lsum; __syncthreads();
  for (int s = 128; s > 0; s >>= 1) {
    if (t < s) red[t] += red[t + s];
    __syncthreads();
  }
  float inv = 1.f / red[0]; __syncthreads();

  int d = t & 63, grp = t >> 6;
  float a = 0.f;
  for (int j = grp; j < 1025; j += 4)
    a += pr[j] * b2f(Vp[(rowbase + j) * 1024 + h * 64 + d]);
  red[t] = a; __syncthreads();
  if (t < 64) {
    float tot = (red[t] + red[t + 64]) + (red[t + 128] + red[t + 192]);
    AO[rowbase * 1024 + h * 64 + t] = f2b(tot * inv);
  }
}

// ---------------------------------------------------------------------------
extern "C" void kernel_launch(void* const* d_in, const int* in_sizes, int n_in,
                              void* d_out, int out_size, void* d_ws, size_t ws_size,
                              hipStream_t stream) {
  const float* q  = (const float*)d_in[0];
  const float* k  = (const float*)d_in[1];
  const float* v  = (const float*)d_in[2];
  const float* Wq = (const float*)d_in[3];
  const float* Wk = (const float*)d_in[4];
  const float* Wv = (const float*)d_in[5];
  const float* Wo = (const float*)d_in[6];
  const float* bo = (const float*)d_in[7];
  float* out = (float*)d_out;

  // workspace (u16 units), 211.3 MB total:
  //   wt:  4M            (Wq^T,Wk^T,Wv^T,Wo^T bf16)
  //   qb:  3*MATEL       (q,k,v converted to padded bf16)  [AO aliases qb]
  //   Qp:  3*MATEL       (projected Q,K,V bf16 padded)
  u16* wt = (u16*)d_ws;
  u16* qb = wt + (size_t)4 * 1024 * 1024;
  u16* Qp = qb + 3 * MATEL;
  u16* Kp = Qp + MATEL;
  u16* Vp = Kp + MATEL;
  u16* AO = qb;  // alias: qb dead after projection GEMM

  k_wtrans<<<dim3(32, 32, 4), dim3(32, 8), 0, stream>>>(Wq, Wk, Wv, Wo, wt);
  k_convert<<<2048, 256, 0, stream>>>(q, k, v, qb);

  // Q/K/V projections (z = 0,1,2): nwg = 8*129*3 = 3096 (%8==0)
  k_gemm<false><<<3096, 256, 0, stream>>>(qb, wt, Qp, nullptr, nullptr, 3096);

  k_attn_nb<<<16 * 1024, 256, 0, stream>>>(Qp, Kp, Vp, AO);
  k_attn_row0<<<256, 256, 0, stream>>>(Qp, Kp, Vp, AO);

  // output projection: nwg = 8*129 = 1032 (%8==0), fp32 out + bias
  k_gemm<true><<<1032, 256, 0, stream>>>(AO, wt + (size_t)3 * 1024 * 1024,
                                         nullptr, out, bo, 1032);
}